// Round 7
// baseline (221.806 us; speedup 1.0000x reference)
//
#include <hip/hip_runtime.h>
#include <stdint.h>

typedef __bf16 bf16;
typedef __attribute__((ext_vector_type(4))) float f32x4;
typedef __attribute__((ext_vector_type(8))) __bf16 bf16x8;
typedef __attribute__((ext_vector_type(4))) __bf16 bf16x4;

#define NB 16      // batch
#define CH 512     // channels
#define HWS 1024   // H*W
#define NHEAD 8
#define DH 64
#define O3 1536    // 3*C
#define LDP 72     // padded LDS pitch (flash)
#define CPQ 136    // qkv C-restage pitch (bf16)
#define CPF 132    // proj C-restage pitch (fp32)

// async global->LDS, 16B per lane; LDS dest = wave-uniform base + lane*16
__device__ __forceinline__ void gload_lds16(const bf16* g, bf16* l) {
    __builtin_amdgcn_global_load_lds(
        (const __attribute__((address_space(1))) unsigned int*)g,
        (__attribute__((address_space(3))) unsigned int*)l,
        16, 0, 0);
}

// ---------------------------------------------------------------- prep: gn stats + weight cvt
__global__ void prep(const float* __restrict__ x, float* __restrict__ stats,
                     const float* __restrict__ wq, const float* __restrict__ wp,
                     bf16* __restrict__ wq_b, bf16* __restrict__ wp_b) {
    int bx = blockIdx.x;
    if (bx < 512) {                 // groupnorm stats: b*32+g
        int b = bx >> 5, g = bx & 31;
        const float4* p = (const float4*)(x + ((size_t)(b * CH + g * 16)) * HWS);
        float s = 0.f, ss = 0.f;
        for (int i = threadIdx.x; i < 4096; i += 256) {
            float4 v = p[i];
            s  += v.x + v.y + v.z + v.w;
            ss += v.x*v.x + v.y*v.y + v.z*v.z + v.w*v.w;
        }
        for (int off = 32; off; off >>= 1) {
            s  += __shfl_xor(s,  off, 64);
            ss += __shfl_xor(ss, off, 64);
        }
        __shared__ float red[8];
        int w = threadIdx.x >> 6;
        if ((threadIdx.x & 63) == 0) { red[w*2] = s; red[w*2+1] = ss; }
        __syncthreads();
        if (threadIdx.x == 0) {
            float S  = red[0] + red[2] + red[4] + red[6];
            float SS = red[1] + red[3] + red[5] + red[7];
            float mean = S * (1.f/16384.f);
            float var  = SS * (1.f/16384.f) - mean*mean;
            stats[bx*2]   = mean;
            stats[bx*2+1] = rsqrtf(var + 1e-5f);
        }
    } else {                        // weight fp32 -> bf16
        int i = (bx - 512) * 256 + threadIdx.x;
        if (i < O3*CH) wq_b[i] = (bf16)wq[i];
        else           wp_b[i - O3*CH] = (bf16)wp[i - O3*CH];
    }
}

// ---------------------------------------------------------------- normalize + transpose -> hT (16384,512) bf16
__global__ void gn_apply_t(const float* __restrict__ x, const float* __restrict__ stats,
                           const float* __restrict__ gamma, const float* __restrict__ beta,
                           bf16* __restrict__ hT) {
    __shared__ float tile[32][33];
    int bx = blockIdx.x;            // 16 * 16 * 32 = 8192 blocks
    int b = bx >> 9;
    int rem = bx & 511;
    int ct = rem >> 5, nt = rem & 31;
    int tx = threadIdx.x & 31, ty = threadIdx.x >> 5;   // ty 0..7
    #pragma unroll
    for (int r = 0; r < 4; ++r) {
        int c = ct*32 + ty + r*8;
        int n = nt*32 + tx;
        float v = x[((size_t)(b * CH + c)) * HWS + n];
        int g = c >> 4;
        float mean = stats[(b*32+g)*2], rstd = stats[(b*32+g)*2+1];
        tile[ty + r*8][tx] = (v - mean) * rstd * gamma[c] + beta[c];
    }
    __syncthreads();
    #pragma unroll
    for (int r = 0; r < 4; ++r) {
        int n = nt*32 + ty + r*8;
        int c = ct*32 + tx;
        hT[((size_t)(b * HWS + n)) * CH + c] = (bf16)tile[tx][ty + r*8];
    }
}

// ---------------------------------------------------------------- qkv GEMM + fused V-transpose
// K-loop staged via global_load_lds (16B), LDS pitch 64 with XOR swizzle applied on the
// GLOBAL source address (lane reads chunk pos^(row&7)) -> conflict-free fragment reads.
// Epilogue identical to round-4 (proven).
__global__ __launch_bounds__(256, 3)
void qkv_gemm(const bf16* __restrict__ W, const bf16* __restrict__ hT,
              const float* __restrict__ bias, bf16* __restrict__ qkv,
              bf16* __restrict__ vT) {
    __shared__ __align__(16) bf16 SMEM[128*CPQ];   // 34816 B (staging uses 32 KB)
    bf16* As = SMEM;            // [128 o][64 k] swizzled, pitch 64
    bf16* Bs = SMEM + 8192;     // [128 bn][64 k]
    int bx = blockIdx.x;                 // 12 * 128 = 1536 blocks
    int po = bx >> 7, qo = bx & 127;     // qo low bits -> XCD locality on hT
    int obase = po*128, bnbase = qo*128;
    int tid = threadIdx.x;
    int lane = tid & 63, w = tid >> 6;
    int quad = lane >> 4, l15 = lane & 15;
    int wm = w >> 1, wn = w & 1;
    int x7 = l15 & 7;
    int srow = lane >> 3, spos = lane & 7;          // wave covers 8 rows x 8 chunks
    int sgc = (spos ^ srow) * 8;                    // swizzled source chunk (elements)

    f32x4 acc[4][4] = {};
    for (int k0 = 0; k0 < 512; k0 += 64) {
        #pragma unroll
        for (int r = 0; r < 4; ++r) {
            int rb = r*32 + w*8;                    // row-group base (multiple of 8)
            gload_lds16(W  + ((size_t)(obase  + rb + srow))*512 + k0 + sgc, &As[rb*64]);
            gload_lds16(hT + ((size_t)(bnbase + rb + srow))*512 + k0 + sgc, &Bs[rb*64]);
        }
        __syncthreads();                            // drains vmcnt -> tiles ready
        #pragma unroll
        for (int ks = 0; ks < 2; ++ks) {
            int ch = (ks*4 + quad) ^ x7;
            bf16x8 af[4], bfv[4];
            #pragma unroll
            for (int mt = 0; mt < 4; ++mt)
                af[mt] = *(const bf16x8*)(&As[(wm*64 + mt*16 + l15)*64 + ch*8]);
            #pragma unroll
            for (int nt = 0; nt < 4; ++nt)
                bfv[nt] = *(const bf16x8*)(&Bs[(wn*64 + nt*16 + l15)*64 + ch*8]);
            #pragma unroll
            for (int mt = 0; mt < 4; ++mt)
                #pragma unroll
                for (int nt = 0; nt < 4; ++nt)
                    acc[mt][nt] = __builtin_amdgcn_mfma_f32_16x16x32_bf16(af[mt], bfv[nt], acc[mt][nt], 0, 0, 0);
        }
        __syncthreads();
    }

    // ---- epilogue: bias, V-direct stores, C restage for Q/K (round-4 exact)
    bf16* Cs = SMEM;                 // [128 bn][CPQ]
    int b = bnbase >> 10;
    int nbase = bnbase & 1023;
    #pragma unroll
    for (int mt = 0; mt < 4; ++mt) {
        int o0 = obase + wm*64 + mt*16 + quad*4;
        float4 bb = *(const float4*)(bias + o0);
        int c192 = o0 % 192;
        bool isV = (c192 >= 128);
        int h = o0 / 192;
        int d0 = c192 - 128;
        #pragma unroll
        for (int nt = 0; nt < 4; ++nt) {
            int bn_l = wn*64 + nt*16 + l15;
            bf16x4 v;
            v[0] = (bf16)(acc[mt][nt][0] + bb.x);
            v[1] = (bf16)(acc[mt][nt][1] + bb.y);
            v[2] = (bf16)(acc[mt][nt][2] + bb.z);
            v[3] = (bf16)(acc[mt][nt][3] + bb.w);
            *(bf16x4*)(&Cs[bn_l*CPQ + (o0 - obase)]) = v;
            if (isV) {
                int key = nbase + bn_l;
                size_t vb_ = ((size_t)((b*8 + h)*64 + d0)) * HWS + key;
                vT[vb_]          = v[0];
                vT[vb_ + HWS]    = v[1];
                vT[vb_ + 2*HWS]  = v[2];
                vT[vb_ + 3*HWS]  = v[3];
            }
        }
    }
    __syncthreads();
    #pragma unroll
    for (int p = 0; p < 8; ++p) {
        int bn_l = p*16 + (tid >> 4);
        int o8 = (tid & 15) * 8;
        if ((obase + o8) % 192 < 128) {
            uint4 v = *(const uint4*)(&Cs[bn_l*CPQ + o8]);
            *(uint4*)(qkv + ((size_t)(bnbase + bn_l)) * O3 + obase + o8) = v;
        }
    }
}

// ---------------------------------------------------------------- flash attention (round-4 verbatim, best measured: 67.7us)
__global__ __launch_bounds__(256, 4)
void flash_attn(const bf16* __restrict__ qkv, const bf16* __restrict__ vT,
                bf16* __restrict__ A2) {
    __shared__ __align__(16) bf16 Ks[64*LDP];
    __shared__ __align__(16) bf16 Vs[64*LDP];
    __shared__ __align__(16) bf16 Ps[4][32*LDP];
    int bx = blockIdx.x;                 // 1024: g = bx&127 (XCD locality), qt = bx>>7
    int g = bx & 127, qt = bx >> 7;
    int b = g >> 3, h = g & 7;
    int tid = threadIdx.x, lane = tid & 63, w = tid >> 6;
    int quad = lane >> 4, l15 = lane & 15;
    const float kLog2 = 0.04419417382415922f * 1.44269504088896341f; // 512^-0.5 * log2(e)

    bf16x8 aq[2][2];
    #pragma unroll
    for (int mt = 0; mt < 2; ++mt) {
        int qrow = qt*128 + w*32 + mt*16 + l15;
        const bf16* qb = qkv + ((size_t)(b * HWS + qrow)) * O3 + h*192;
        aq[mt][0] = *(const bf16x8*)(qb + quad*8);
        aq[mt][1] = *(const bf16x8*)(qb + 32 + quad*8);
    }

    f32x4 acc[2][4] = {};
    float L[2] = {0.f, 0.f};

    int r0 = tid >> 3, d0 = (tid & 7) * 8;
    int r1 = r0 + 32;
    const bf16* kp0 = qkv + ((size_t)(b * HWS + r0)) * O3 + h*192 + 64 + d0;
    const bf16* kp1 = qkv + ((size_t)(b * HWS + r1)) * O3 + h*192 + 64 + d0;
    const bf16* vp0 = vT + ((size_t)(g * DH + r0)) * HWS + d0;
    const bf16* vp1 = vT + ((size_t)(g * DH + r1)) * HWS + d0;
    bf16* ksd0 = &Ks[r0*LDP + d0];
    bf16* ksd1 = &Ks[r1*LDP + d0];
    bf16* vsd0 = &Vs[r0*LDP + d0];
    bf16* vsd1 = &Vs[r1*LDP + d0];

    uint4 ka = *(const uint4*)(kp0);
    uint4 kb = *(const uint4*)(kp1);
    uint4 va = *(const uint4*)(vp0);
    uint4 vb = *(const uint4*)(vp1);

    for (int kt = 0; kt < 16; ++kt) {
        __syncthreads();
        *(uint4*)ksd0 = ka;
        *(uint4*)ksd1 = kb;
        *(uint4*)vsd0 = va;
        *(uint4*)vsd1 = vb;
        __syncthreads();
        if (kt < 15) {
            size_t ko = (size_t)(kt+1) * 64 * O3;
            size_t vo = (size_t)(kt+1) * 64;
            ka = *(const uint4*)(kp0 + ko);
            kb = *(const uint4*)(kp1 + ko);
            va = *(const uint4*)(vp0 + vo);
            vb = *(const uint4*)(vp1 + vo);
        }

        #pragma unroll
        for (int nt = 0; nt < 4; ++nt) {
            bf16x8 ak0 = *(const bf16x8*)(&Ks[(nt*16 + l15)*LDP + quad*8]);
            bf16x8 ak1 = *(const bf16x8*)(&Ks[(nt*16 + l15)*LDP + 32 + quad*8]);
            #pragma unroll
            for (int mt = 0; mt < 2; ++mt) {
                f32x4 z = {};
                z = __builtin_amdgcn_mfma_f32_16x16x32_bf16(ak0, aq[mt][0], z, 0, 0, 0);
                z = __builtin_amdgcn_mfma_f32_16x16x32_bf16(ak1, aq[mt][1], z, 0, 0, 0);
                bf16x4 p;
                #pragma unroll
                for (int r = 0; r < 4; ++r) {
                    float e = exp2f(z[r] * kLog2);
                    L[mt] += e;
                    p[r] = (bf16)e;
                }
                *(bf16x4*)(&Ps[w][(mt*16 + l15)*LDP + nt*16 + quad*4]) = p;
            }
        }
        bf16x8 ap[2][2];
        #pragma unroll
        for (int mt = 0; mt < 2; ++mt) {
            ap[mt][0] = *(const bf16x8*)(&Ps[w][(mt*16 + l15)*LDP + quad*8]);
            ap[mt][1] = *(const bf16x8*)(&Ps[w][(mt*16 + l15)*LDP + 32 + quad*8]);
        }
        #pragma unroll
        for (int dt = 0; dt < 4; ++dt) {
            bf16x8 bv0 = *(const bf16x8*)(&Vs[(dt*16 + l15)*LDP + quad*8]);
            bf16x8 bv1 = *(const bf16x8*)(&Vs[(dt*16 + l15)*LDP + 32 + quad*8]);
            #pragma unroll
            for (int mt = 0; mt < 2; ++mt) {
                acc[mt][dt] = __builtin_amdgcn_mfma_f32_16x16x32_bf16(ap[mt][0], bv0, acc[mt][dt], 0, 0, 0);
                acc[mt][dt] = __builtin_amdgcn_mfma_f32_16x16x32_bf16(ap[mt][1], bv1, acc[mt][dt], 0, 0, 0);
            }
        }
    }

    float Linv[2][4];
    #pragma unroll
    for (int mt = 0; mt < 2; ++mt) {
        float Lf = L[mt];
        Lf += __shfl_xor(Lf, 16, 64);
        Lf += __shfl_xor(Lf, 32, 64);
        #pragma unroll
        for (int r = 0; r < 4; ++r)
            Linv[mt][r] = 1.f / __shfl(Lf, quad*4 + r, 64);
    }

    __syncthreads();
    #pragma unroll
    for (int mt = 0; mt < 2; ++mt)
        #pragma unroll
        for (int dt = 0; dt < 4; ++dt)
            #pragma unroll
            for (int r = 0; r < 4; ++r)
                Ps[w][(mt*16 + quad*4 + r)*LDP + dt*16 + l15] = (bf16)(acc[mt][dt][r] * Linv[mt][r]);

    int bp = g & 15;          // output batch (reference's head-major quirk)
    int hp = g >> 4;          // output head slot
    #pragma unroll
    for (int cc = 0; cc < 4; ++cc) {
        int c = cc*64 + lane;
        int row = c >> 3, dcc = c & 7;
        uint4 v = *(const uint4*)(&Ps[w][row*LDP + dcc*8]);
        size_t idx = ((size_t)(bp * HWS + qt*128 + w*32 + row)) * CH + hp*64 + dcc*8;
        *(uint4*)(A2 + idx) = v;
    }
}

// ---------------------------------------------------------------- proj GEMM + bias + residual
// Same global_load_lds staging; epilogue identical to round-4.
__global__ __launch_bounds__(256, 3)
void proj_gemm(const bf16* __restrict__ A2, const bf16* __restrict__ Wp,
               const float* __restrict__ bias, const float* __restrict__ x,
               float* __restrict__ out) {
    __shared__ __align__(16) bf16 SMEM[16896];     // 33792 B (staging 32 KB)
    bf16* As = SMEM;            // [128 bn][64 k] swizzled, pitch 64
    bf16* Bs = SMEM + 8192;     // [128 o][64 k]
    int bx = blockIdx.x;                 // 512
    int po = bx >> 7, qo = bx & 127;
    int obase = po*128, bnbase = qo*128;
    int tid = threadIdx.x;
    int lane = tid & 63, w = tid >> 6;
    int quad = lane >> 4, l15 = lane & 15;
    int wm = w >> 1, wn = w & 1;
    int x7 = l15 & 7;
    int srow = lane >> 3, spos = lane & 7;
    int sgc = (spos ^ srow) * 8;

    f32x4 acc[4][4] = {};
    for (int k0 = 0; k0 < 512; k0 += 64) {
        #pragma unroll
        for (int r = 0; r < 4; ++r) {
            int rb = r*32 + w*8;
            gload_lds16(A2 + ((size_t)(bnbase + rb + srow))*512 + k0 + sgc, &As[rb*64]);
            gload_lds16(Wp + ((size_t)(obase  + rb + srow))*512 + k0 + sgc, &Bs[rb*64]);
        }
        __syncthreads();
        #pragma unroll
        for (int ks = 0; ks < 2; ++ks) {
            int ch = (ks*4 + quad) ^ x7;
            bf16x8 af[4], bfv[4];
            #pragma unroll
            for (int mt = 0; mt < 4; ++mt)
                af[mt] = *(const bf16x8*)(&As[(wm*64 + mt*16 + l15)*64 + ch*8]);
            #pragma unroll
            for (int nt = 0; nt < 4; ++nt)
                bfv[nt] = *(const bf16x8*)(&Bs[(wn*64 + nt*16 + l15)*64 + ch*8]);
            #pragma unroll
            for (int mt = 0; mt < 4; ++mt)
                #pragma unroll
                for (int nt = 0; nt < 4; ++nt)
                    acc[mt][nt] = __builtin_amdgcn_mfma_f32_16x16x32_bf16(af[mt], bfv[nt], acc[mt][nt], 0, 0, 0);
        }
        __syncthreads();
    }

    // epilogue (round-4 exact): bn = bnbase + wm*64 + mt*16 + quad*4 + r, o = obase + wn*64 + nt*16 + l15
    float* Cf = (float*)SMEM;        // [64 bn][CPF] fp32 per half-pass
    int bb = bnbase >> 10;
    int nbase = bnbase & 1023;
    #pragma unroll
    for (int hh = 0; hh < 2; ++hh) {
        if (wm == hh) {
            #pragma unroll
            for (int mt = 0; mt < 4; ++mt)
                #pragma unroll
                for (int nt = 0; nt < 4; ++nt)
                    #pragma unroll
                    for (int r = 0; r < 4; ++r)
                        Cf[(mt*16 + quad*4 + r)*CPF + wn*64 + nt*16 + l15] = acc[mt][nt][r];
        }
        __syncthreads();
        #pragma unroll
        for (int p = 0; p < 4; ++p) {
            int ol = p*32 + (tid >> 3);
            int nl0 = (tid & 7) * 8;
            int o = obase + ol;
            float bv = bias[o];
            #pragma unroll
            for (int jj = 0; jj < 2; ++jj) {
                int nl = nl0 + jj*4;
                size_t idx = ((size_t)(bb * CH + o)) * HWS + nbase + hh*64 + nl;
                float4 xr = *(const float4*)(x + idx);
                float4 res;
                res.x = Cf[(nl+0)*CPF + ol] + bv + xr.x;
                res.y = Cf[(nl+1)*CPF + ol] + bv + xr.y;
                res.z = Cf[(nl+2)*CPF + ol] + bv + xr.z;
                res.w = Cf[(nl+3)*CPF + ol] + bv + xr.w;
                *(float4*)(out + idx) = res;
            }
        }
        __syncthreads();
    }
}

// ---------------------------------------------------------------- launch
extern "C" void kernel_launch(void* const* d_in, const int* in_sizes, int n_in,
                              void* d_out, int out_size, void* d_ws, size_t ws_size,
                              hipStream_t stream) {
    const float* x      = (const float*)d_in[0];
    const float* gamma  = (const float*)d_in[1];
    const float* beta   = (const float*)d_in[2];
    const float* w_qkv  = (const float*)d_in[3];
    const float* b_qkv  = (const float*)d_in[4];
    const float* w_proj = (const float*)d_in[5];
    const float* b_proj = (const float*)d_in[6];
    float* out = (float*)d_out;

    char* ws = (char*)d_ws;
    float* stats = (float*)(ws + 0);                       //   4 KB
    bf16*  wq_b  = (bf16*)(ws + 4096);                     // 1.5 MB
    bf16*  wp_b  = (bf16*)(ws + 1576960);                  // 0.5 MB
    bf16*  hT    = (bf16*)(ws + 2101248);                  // 16 MB (aliased by A2 later)
    bf16*  qkv   = (bf16*)(ws + 18878464);                 // 48 MB (V slots unused)
    bf16*  vT    = (bf16*)(ws + 69210112);                 // 16 MB
    bf16*  A2    = hT;                                     // reuse: hT dead after qkv_gemm

    prep       <<<4608, 256, 0, stream>>>(x, stats, w_qkv, w_proj, wq_b, wp_b);
    gn_apply_t <<<8192, 256, 0, stream>>>(x, stats, gamma, beta, hT);
    qkv_gemm   <<<1536, 256, 0, stream>>>(wq_b, hT, b_qkv, qkv, vT);
    flash_attn <<<1024, 256, 0, stream>>>(qkv, vT, A2);
    proj_gemm  <<<512,  256, 0, stream>>>(A2, wp_b, b_proj, x, out);
}

// Round 9
// 205.548 us; speedup vs baseline: 1.0791x; 1.0791x over previous
//
#include <hip/hip_runtime.h>
#include <stdint.h>

typedef __bf16 bf16;
typedef __attribute__((ext_vector_type(4))) float f32x4;
typedef __attribute__((ext_vector_type(8))) __bf16 bf16x8;
typedef __attribute__((ext_vector_type(4))) __bf16 bf16x4;

#define NB 16      // batch
#define CH 512     // channels
#define HWS 1024   // H*W
#define NHEAD 8
#define DH 64
#define O3 1536    // 3*C
#define LDP 72     // padded LDS pitch (flash)
#define CPQ 136    // qkv C-restage pitch (bf16)
#define CPF 132    // proj C-restage pitch (fp32)

// async global->LDS, 16B per lane; LDS dest = wave-uniform base + lane*16
__device__ __forceinline__ void gload_lds16(const bf16* g, bf16* l) {
    __builtin_amdgcn_global_load_lds(
        (const __attribute__((address_space(1))) unsigned int*)g,
        (__attribute__((address_space(3))) unsigned int*)l,
        16, 0, 0);
}

// raw v_exp_f32 (2^x) via compiler-visible intrinsic — skips OCML's denormal guard
// but keeps correct trans-use hazard scheduling (round-8's opaque asm version NaN'd).
#if defined(__has_builtin) && __has_builtin(__builtin_amdgcn_exp2f)
__device__ __forceinline__ float fast_exp2(float x) { return __builtin_amdgcn_exp2f(x); }
#else
__device__ __forceinline__ float fast_exp2(float x) { return exp2f(x); }
#endif

// ---------------------------------------------------------------- prep: gn stats + weight cvt
__global__ void prep(const float* __restrict__ x, float* __restrict__ stats,
                     const float* __restrict__ wq, const float* __restrict__ wp,
                     bf16* __restrict__ wq_b, bf16* __restrict__ wp_b) {
    int bx = blockIdx.x;
    if (bx < 512) {                 // groupnorm stats: b*32+g
        int b = bx >> 5, g = bx & 31;
        const float4* p = (const float4*)(x + ((size_t)(b * CH + g * 16)) * HWS);
        float s = 0.f, ss = 0.f;
        for (int i = threadIdx.x; i < 4096; i += 256) {
            float4 v = p[i];
            s  += v.x + v.y + v.z + v.w;
            ss += v.x*v.x + v.y*v.y + v.z*v.z + v.w*v.w;
        }
        for (int off = 32; off; off >>= 1) {
            s  += __shfl_xor(s,  off, 64);
            ss += __shfl_xor(ss, off, 64);
        }
        __shared__ float red[8];
        int w = threadIdx.x >> 6;
        if ((threadIdx.x & 63) == 0) { red[w*2] = s; red[w*2+1] = ss; }
        __syncthreads();
        if (threadIdx.x == 0) {
            float S  = red[0] + red[2] + red[4] + red[6];
            float SS = red[1] + red[3] + red[5] + red[7];
            float mean = S * (1.f/16384.f);
            float var  = SS * (1.f/16384.f) - mean*mean;
            stats[bx*2]   = mean;
            stats[bx*2+1] = rsqrtf(var + 1e-5f);
        }
    } else {                        // weight fp32 -> bf16
        int i = (bx - 512) * 256 + threadIdx.x;
        if (i < O3*CH) wq_b[i] = (bf16)wq[i];
        else           wp_b[i - O3*CH] = (bf16)wp[i - O3*CH];
    }
}

// ---------------------------------------------------------------- normalize + transpose -> hT (16384,512) bf16
__global__ void gn_apply_t(const float* __restrict__ x, const float* __restrict__ stats,
                           const float* __restrict__ gamma, const float* __restrict__ beta,
                           bf16* __restrict__ hT) {
    __shared__ float tile[32][33];
    int bx = blockIdx.x;            // 16 * 16 * 32 = 8192 blocks
    int b = bx >> 9;
    int rem = bx & 511;
    int ct = rem >> 5, nt = rem & 31;
    int tx = threadIdx.x & 31, ty = threadIdx.x >> 5;   // ty 0..7
    #pragma unroll
    for (int r = 0; r < 4; ++r) {
        int c = ct*32 + ty + r*8;
        int n = nt*32 + tx;
        float v = x[((size_t)(b * CH + c)) * HWS + n];
        int g = c >> 4;
        float mean = stats[(b*32+g)*2], rstd = stats[(b*32+g)*2+1];
        tile[ty + r*8][tx] = (v - mean) * rstd * gamma[c] + beta[c];
    }
    __syncthreads();
    #pragma unroll
    for (int r = 0; r < 4; ++r) {
        int n = nt*32 + ty + r*8;
        int c = ct*32 + tx;
        hT[((size_t)(b * HWS + n)) * CH + c] = (bf16)tile[tx][ty + r*8];
    }
}

// ---------------------------------------------------------------- qkv GEMM + fused V-transpose (round-7)
__global__ __launch_bounds__(256, 3)
void qkv_gemm(const bf16* __restrict__ W, const bf16* __restrict__ hT,
              const float* __restrict__ bias, bf16* __restrict__ qkv,
              bf16* __restrict__ vT) {
    __shared__ __align__(16) bf16 SMEM[128*CPQ];   // 34816 B (staging uses 32 KB)
    bf16* As = SMEM;            // [128 o][64 k] swizzled, pitch 64
    bf16* Bs = SMEM + 8192;     // [128 bn][64 k]
    int bx = blockIdx.x;                 // 12 * 128 = 1536 blocks
    int po = bx >> 7, qo = bx & 127;     // qo low bits -> XCD locality on hT
    int obase = po*128, bnbase = qo*128;
    int tid = threadIdx.x;
    int lane = tid & 63, w = tid >> 6;
    int quad = lane >> 4, l15 = lane & 15;
    int wm = w >> 1, wn = w & 1;
    int x7 = l15 & 7;
    int srow = lane >> 3, spos = lane & 7;          // wave covers 8 rows x 8 chunks
    int sgc = (spos ^ srow) * 8;                    // swizzled source chunk (elements)

    f32x4 acc[4][4] = {};
    for (int k0 = 0; k0 < 512; k0 += 64) {
        #pragma unroll
        for (int r = 0; r < 4; ++r) {
            int rb = r*32 + w*8;                    // row-group base (multiple of 8)
            gload_lds16(W  + ((size_t)(obase  + rb + srow))*512 + k0 + sgc, &As[rb*64]);
            gload_lds16(hT + ((size_t)(bnbase + rb + srow))*512 + k0 + sgc, &Bs[rb*64]);
        }
        __syncthreads();                            // drains vmcnt -> tiles ready
        #pragma unroll
        for (int ks = 0; ks < 2; ++ks) {
            int ch = (ks*4 + quad) ^ x7;
            bf16x8 af[4], bfv[4];
            #pragma unroll
            for (int mt = 0; mt < 4; ++mt)
                af[mt] = *(const bf16x8*)(&As[(wm*64 + mt*16 + l15)*64 + ch*8]);
            #pragma unroll
            for (int nt = 0; nt < 4; ++nt)
                bfv[nt] = *(const bf16x8*)(&Bs[(wn*64 + nt*16 + l15)*64 + ch*8]);
            #pragma unroll
            for (int mt = 0; mt < 4; ++mt)
                #pragma unroll
                for (int nt = 0; nt < 4; ++nt)
                    acc[mt][nt] = __builtin_amdgcn_mfma_f32_16x16x32_bf16(af[mt], bfv[nt], acc[mt][nt], 0, 0, 0);
        }
        __syncthreads();
    }

    // ---- epilogue: bias, V-direct stores, C restage for Q/K (round-4 exact)
    bf16* Cs = SMEM;                 // [128 bn][CPQ]
    int b = bnbase >> 10;
    int nbase = bnbase & 1023;
    #pragma unroll
    for (int mt = 0; mt < 4; ++mt) {
        int o0 = obase + wm*64 + mt*16 + quad*4;
        float4 bb = *(const float4*)(bias + o0);
        int c192 = o0 % 192;
        bool isV = (c192 >= 128);
        int h = o0 / 192;
        int d0 = c192 - 128;
        #pragma unroll
        for (int nt = 0; nt < 4; ++nt) {
            int bn_l = wn*64 + nt*16 + l15;
            bf16x4 v;
            v[0] = (bf16)(acc[mt][nt][0] + bb.x);
            v[1] = (bf16)(acc[mt][nt][1] + bb.y);
            v[2] = (bf16)(acc[mt][nt][2] + bb.z);
            v[3] = (bf16)(acc[mt][nt][3] + bb.w);
            *(bf16x4*)(&Cs[bn_l*CPQ + (o0 - obase)]) = v;
            if (isV) {
                int key = nbase + bn_l;
                size_t vb_ = ((size_t)((b*8 + h)*64 + d0)) * HWS + key;
                vT[vb_]          = v[0];
                vT[vb_ + HWS]    = v[1];
                vT[vb_ + 2*HWS]  = v[2];
                vT[vb_ + 3*HWS]  = v[3];
            }
        }
    }
    __syncthreads();
    #pragma unroll
    for (int p = 0; p < 8; ++p) {
        int bn_l = p*16 + (tid >> 4);
        int o8 = (tid & 15) * 8;
        if ((obase + o8) % 192 < 128) {
            uint4 v = *(const uint4*)(&Cs[bn_l*CPQ + o8]);
            *(uint4*)(qkv + ((size_t)(bnbase + bn_l)) * O3 + obase + o8) = v;
        }
    }
}

// ---------------------------------------------------------------- flash attention (v5b)
// round-4 structure + 3 VALU cuts: raw exp2 intrinsic, scale folded into Q regs,
// 4-way partial L accumulators (breaks the dependent add chain).
__global__ __launch_bounds__(256, 4)
void flash_attn(const bf16* __restrict__ qkv, const bf16* __restrict__ vT,
                bf16* __restrict__ A2) {
    __shared__ __align__(16) bf16 Ks[64*LDP];
    __shared__ __align__(16) bf16 Vs[64*LDP];
    __shared__ __align__(16) bf16 Ps[4][32*LDP];
    int bx = blockIdx.x;                 // 1024: g = bx&127 (XCD locality), qt = bx>>7
    int g = bx & 127, qt = bx >> 7;
    int b = g >> 3, h = g & 7;
    int tid = threadIdx.x, lane = tid & 63, w = tid >> 6;
    int quad = lane >> 4, l15 = lane & 15;
    const float kLog2 = 0.04419417382415922f * 1.44269504088896341f; // 512^-0.5 * log2(e)

    bf16x8 aq[2][2];
    #pragma unroll
    for (int mt = 0; mt < 2; ++mt) {
        int qrow = qt*128 + w*32 + mt*16 + l15;
        const bf16* qb = qkv + ((size_t)(b * HWS + qrow)) * O3 + h*192;
        aq[mt][0] = *(const bf16x8*)(qb + quad*8);
        aq[mt][1] = *(const bf16x8*)(qb + 32 + quad*8);
        // fold softmax scale & log2(e) into Q once: saves 512 v_mul per lane in the hot loop
        #pragma unroll
        for (int j = 0; j < 8; ++j) {
            aq[mt][0][j] = (bf16)((float)aq[mt][0][j] * kLog2);
            aq[mt][1][j] = (bf16)((float)aq[mt][1][j] * kLog2);
        }
    }

    f32x4 acc[2][4] = {};
    f32x4 L4[2] = {};                    // per-r partial row sums (independent add chains)

    int r0 = tid >> 3, d0 = (tid & 7) * 8;
    int r1 = r0 + 32;
    const bf16* kp0 = qkv + ((size_t)(b * HWS + r0)) * O3 + h*192 + 64 + d0;
    const bf16* kp1 = qkv + ((size_t)(b * HWS + r1)) * O3 + h*192 + 64 + d0;
    const bf16* vp0 = vT + ((size_t)(g * DH + r0)) * HWS + d0;
    const bf16* vp1 = vT + ((size_t)(g * DH + r1)) * HWS + d0;
    bf16* ksd0 = &Ks[r0*LDP + d0];
    bf16* ksd1 = &Ks[r1*LDP + d0];
    bf16* vsd0 = &Vs[r0*LDP + d0];
    bf16* vsd1 = &Vs[r1*LDP + d0];

    uint4 ka = *(const uint4*)(kp0);
    uint4 kb = *(const uint4*)(kp1);
    uint4 va = *(const uint4*)(vp0);
    uint4 vb = *(const uint4*)(vp1);

    for (int kt = 0; kt < 16; ++kt) {
        __syncthreads();
        *(uint4*)ksd0 = ka;
        *(uint4*)ksd1 = kb;
        *(uint4*)vsd0 = va;
        *(uint4*)vsd1 = vb;
        __syncthreads();
        if (kt < 15) {
            size_t ko = (size_t)(kt+1) * 64 * O3;
            size_t vo = (size_t)(kt+1) * 64;
            ka = *(const uint4*)(kp0 + ko);
            kb = *(const uint4*)(kp1 + ko);
            va = *(const uint4*)(vp0 + vo);
            vb = *(const uint4*)(vp1 + vo);
        }

        // S^T = K x Q^T (pre-scaled): lane holds q=l15, keys nt*16+quad*4+r
        #pragma unroll
        for (int nt = 0; nt < 4; ++nt) {
            bf16x8 ak0 = *(const bf16x8*)(&Ks[(nt*16 + l15)*LDP + quad*8]);
            bf16x8 ak1 = *(const bf16x8*)(&Ks[(nt*16 + l15)*LDP + 32 + quad*8]);
            #pragma unroll
            for (int mt = 0; mt < 2; ++mt) {
                f32x4 z = {};
                z = __builtin_amdgcn_mfma_f32_16x16x32_bf16(ak0, aq[mt][0], z, 0, 0, 0);
                z = __builtin_amdgcn_mfma_f32_16x16x32_bf16(ak1, aq[mt][1], z, 0, 0, 0);
                bf16x4 p;
                #pragma unroll
                for (int r = 0; r < 4; ++r) {
                    float e = fast_exp2(z[r]);
                    L4[mt][r] += e;
                    p[r] = (bf16)e;
                }
                *(bf16x4*)(&Ps[w][(mt*16 + l15)*LDP + nt*16 + quad*4]) = p;
            }
        }
        bf16x8 ap[2][2];
        #pragma unroll
        for (int mt = 0; mt < 2; ++mt) {
            ap[mt][0] = *(const bf16x8*)(&Ps[w][(mt*16 + l15)*LDP + quad*8]);
            ap[mt][1] = *(const bf16x8*)(&Ps[w][(mt*16 + l15)*LDP + 32 + quad*8]);
        }
        #pragma unroll
        for (int dt = 0; dt < 4; ++dt) {
            bf16x8 bv0 = *(const bf16x8*)(&Vs[(dt*16 + l15)*LDP + quad*8]);
            bf16x8 bv1 = *(const bf16x8*)(&Vs[(dt*16 + l15)*LDP + 32 + quad*8]);
            #pragma unroll
            for (int mt = 0; mt < 2; ++mt) {
                acc[mt][dt] = __builtin_amdgcn_mfma_f32_16x16x32_bf16(ap[mt][0], bv0, acc[mt][dt], 0, 0, 0);
                acc[mt][dt] = __builtin_amdgcn_mfma_f32_16x16x32_bf16(ap[mt][1], bv1, acc[mt][dt], 0, 0, 0);
            }
        }
    }

    float Linv[2][4];
    #pragma unroll
    for (int mt = 0; mt < 2; ++mt) {
        float Lf = (L4[mt][0] + L4[mt][1]) + (L4[mt][2] + L4[mt][3]);
        Lf += __shfl_xor(Lf, 16, 64);
        Lf += __shfl_xor(Lf, 32, 64);
        #pragma unroll
        for (int r = 0; r < 4; ++r)
            Linv[mt][r] = 1.f / __shfl(Lf, quad*4 + r, 64);
    }

    __syncthreads();
    #pragma unroll
    for (int mt = 0; mt < 2; ++mt)
        #pragma unroll
        for (int dt = 0; dt < 4; ++dt)
            #pragma unroll
            for (int r = 0; r < 4; ++r)
                Ps[w][(mt*16 + quad*4 + r)*LDP + dt*16 + l15] = (bf16)(acc[mt][dt][r] * Linv[mt][r]);

    int bp = g & 15;          // output batch (reference's head-major quirk)
    int hp = g >> 4;          // output head slot
    #pragma unroll
    for (int cc = 0; cc < 4; ++cc) {
        int c = cc*64 + lane;
        int row = c >> 3, dcc = c & 7;
        uint4 v = *(const uint4*)(&Ps[w][row*LDP + dcc*8]);
        size_t idx = ((size_t)(bp * HWS + qt*128 + w*32 + row)) * CH + hp*64 + dcc*8;
        *(uint4*)(A2 + idx) = v;
    }
}

// ---------------------------------------------------------------- proj GEMM + bias + residual (round-7)
__global__ __launch_bounds__(256, 3)
void proj_gemm(const bf16* __restrict__ A2, const bf16* __restrict__ Wp,
               const float* __restrict__ bias, const float* __restrict__ x,
               float* __restrict__ out) {
    __shared__ __align__(16) bf16 SMEM[16896];     // 33792 B (staging 32 KB)
    bf16* As = SMEM;            // [128 bn][64 k] swizzled, pitch 64
    bf16* Bs = SMEM + 8192;     // [128 o][64 k]
    int bx = blockIdx.x;                 // 512
    int po = bx >> 7, qo = bx & 127;
    int obase = po*128, bnbase = qo*128;
    int tid = threadIdx.x;
    int lane = tid & 63, w = tid >> 6;
    int quad = lane >> 4, l15 = lane & 15;
    int wm = w >> 1, wn = w & 1;
    int x7 = l15 & 7;
    int srow = lane >> 3, spos = lane & 7;
    int sgc = (spos ^ srow) * 8;

    f32x4 acc[4][4] = {};
    for (int k0 = 0; k0 < 512; k0 += 64) {
        #pragma unroll
        for (int r = 0; r < 4; ++r) {
            int rb = r*32 + w*8;
            gload_lds16(A2 + ((size_t)(bnbase + rb + srow))*512 + k0 + sgc, &As[rb*64]);
            gload_lds16(Wp + ((size_t)(obase  + rb + srow))*512 + k0 + sgc, &Bs[rb*64]);
        }
        __syncthreads();
        #pragma unroll
        for (int ks = 0; ks < 2; ++ks) {
            int ch = (ks*4 + quad) ^ x7;
            bf16x8 af[4], bfv[4];
            #pragma unroll
            for (int mt = 0; mt < 4; ++mt)
                af[mt] = *(const bf16x8*)(&As[(wm*64 + mt*16 + l15)*64 + ch*8]);
            #pragma unroll
            for (int nt = 0; nt < 4; ++nt)
                bfv[nt] = *(const bf16x8*)(&Bs[(wn*64 + nt*16 + l15)*64 + ch*8]);
            #pragma unroll
            for (int mt = 0; mt < 4; ++mt)
                #pragma unroll
                for (int nt = 0; nt < 4; ++nt)
                    acc[mt][nt] = __builtin_amdgcn_mfma_f32_16x16x32_bf16(af[mt], bfv[nt], acc[mt][nt], 0, 0, 0);
        }
        __syncthreads();
    }

    // epilogue (round-4 exact): bn = bnbase + wm*64 + mt*16 + quad*4 + r, o = obase + wn*64 + nt*16 + l15
    float* Cf = (float*)SMEM;        // [64 bn][CPF] fp32 per half-pass
    int bb = bnbase >> 10;
    int nbase = bnbase & 1023;
    #pragma unroll
    for (int hh = 0; hh < 2; ++hh) {
        if (wm == hh) {
            #pragma unroll
            for (int mt = 0; mt < 4; ++mt)
                #pragma unroll
                for (int nt = 0; nt < 4; ++nt)
                    #pragma unroll
                    for (int r = 0; r < 4; ++r)
                        Cf[(mt*16 + quad*4 + r)*CPF + wn*64 + nt*16 + l15] = acc[mt][nt][r];
        }
        __syncthreads();
        #pragma unroll
        for (int p = 0; p < 4; ++p) {
            int ol = p*32 + (tid >> 3);
            int nl0 = (tid & 7) * 8;
            int o = obase + ol;
            float bv = bias[o];
            #pragma unroll
            for (int jj = 0; jj < 2; ++jj) {
                int nl = nl0 + jj*4;
                size_t idx = ((size_t)(bb * CH + o)) * HWS + nbase + hh*64 + nl;
                float4 xr = *(const float4*)(x + idx);
                float4 res;
                res.x = Cf[(nl+0)*CPF + ol] + bv + xr.x;
                res.y = Cf[(nl+1)*CPF + ol] + bv + xr.y;
                res.z = Cf[(nl+2)*CPF + ol] + bv + xr.z;
                res.w = Cf[(nl+3)*CPF + ol] + bv + xr.w;
                *(float4*)(out + idx) = res;
            }
        }
        __syncthreads();
    }
}

// ---------------------------------------------------------------- launch
extern "C" void kernel_launch(void* const* d_in, const int* in_sizes, int n_in,
                              void* d_out, int out_size, void* d_ws, size_t ws_size,
                              hipStream_t stream) {
    const float* x      = (const float*)d_in[0];
    const float* gamma  = (const float*)d_in[1];
    const float* beta   = (const float*)d_in[2];
    const float* w_qkv  = (const float*)d_in[3];
    const float* b_qkv  = (const float*)d_in[4];
    const float* w_proj = (const float*)d_in[5];
    const float* b_proj = (const float*)d_in[6];
    float* out = (float*)d_out;

    char* ws = (char*)d_ws;
    float* stats = (float*)(ws + 0);                       //   4 KB
    bf16*  wq_b  = (bf16*)(ws + 4096);                     // 1.5 MB
    bf16*  wp_b  = (bf16*)(ws + 1576960);                  // 0.5 MB
    bf16*  hT    = (bf16*)(ws + 2101248);                  // 16 MB (aliased by A2 later)
    bf16*  qkv   = (bf16*)(ws + 18878464);                 // 48 MB (V slots unused)
    bf16*  vT    = (bf16*)(ws + 69210112);                 // 16 MB
    bf16*  A2    = hT;                                     // reuse: hT dead after qkv_gemm

    prep       <<<4608, 256, 0, stream>>>(x, stats, w_qkv, w_proj, wq_b, wp_b);
    gn_apply_t <<<8192, 256, 0, stream>>>(x, stats, gamma, beta, hT);
    qkv_gemm   <<<1536, 256, 0, stream>>>(wq_b, hT, b_qkv, qkv, vT);
    flash_attn <<<1024, 256, 0, stream>>>(qkv, vT, A2);
    proj_gemm  <<<512,  256, 0, stream>>>(A2, wp_b, b_proj, x, out);
}